// Round 17
// baseline (160.965 us; speedup 1.0000x reference)
//
#include <hip/hip_runtime.h>

#define BB 4
#define NN 2048
#define FF 128
#define NP 2176  // padded WhT row stride (shorts)
#define ALPHA 0.2f
#define SHIFT_C 16.0f  // exp(x-16): x=LR(f1+f2) bounded ~|10|; masked -> p=0 via bit-multiply

typedef short bf16x8 __attribute__((ext_vector_type(8)));
typedef float f32x4 __attribute__((ext_vector_type(4)));
typedef unsigned u32;

__device__ inline short f2bf(float f) {  // RNE float -> bf16 bits
    union { float f; unsigned u; } v; v.f = f;
    unsigned r = (v.u + 0x7FFFu + ((v.u >> 16) & 1u)) >> 16;
    return (short)r;
}
__device__ inline float bf2f(short s) {
    union { float f; unsigned u; } v;
    v.u = ((unsigned)(unsigned short)s) << 16;
    return v.f;
}

// ---------------------------------------------------------------------------
// k_wh v3: v2 body (passed R11/R12/R14-R16) with the f-output folded for
// k_attn's cheap-EV: stores f2s = f2 - SHIFT and f2a = ALPHA*f2 - SHIFT
// instead of raw f2 (EV then needs no mul/sub: max(f1+f2s, af1+f2a)).
// ---------------------------------------------------------------------------
__global__ __launch_bounds__(256) void k_wh(const float* __restrict__ h,
                                            const float* __restrict__ W,
                                            const float* __restrict__ a,
                                            const int* __restrict__ adj,
                                            short* __restrict__ WhHiT,
                                            short* __restrict__ WhLoT,
                                            float* __restrict__ f1,
                                            float* __restrict__ f2s,
                                            float* __restrict__ f2a,
                                            u32* __restrict__ adjp) {
    __shared__ float Wa[2 * FF];
    __shared__ float hs[16 * 132];  // 8.25 KB
    int tid = threadIdx.x;
    int r0 = blockIdx.x * 16;

    {
        int fin = tid & 127;
        const float* av = (tid < 128) ? a : (a + FF);
        const float* wr = W + (size_t)fin * FF;
        float s = 0.f;
        for (int o = 0; o < FF; o += 4) {
            float4 wv = *(const float4*)(wr + o);
            float4 avv = *(const float4*)(av + o);
            s += wv.x * avv.x + wv.y * avv.y + wv.z * avv.z + wv.w * avv.w;
        }
        Wa[(tid < 128 ? 0 : FF) + fin] = s;
    }
    {
        const float4* src = (const float4*)(h + (size_t)r0 * FF);
        float4* dst = (float4*)hs;
        dst[tid] = src[tid];
        dst[256 + tid] = src[256 + tid];
    }
    {
        int g = blockIdx.x * 256 + tid;
        int row = g >> 6, wd = g & 63;
        const int4* ar = (const int4*)(adj + (size_t)row * NN + wd * 32);
        u32 word = 0;
#pragma unroll
        for (int q = 0; q < 8; ++q) {
            int4 v = ar[q];
            word |= (u32)(v.x > 0) << (q * 4);
            word |= (u32)(v.y > 0) << (q * 4 + 1);
            word |= (u32)(v.z > 0) << (q * 4 + 2);
            word |= (u32)(v.w > 0) << (q * 4 + 3);
        }
        adjp[row * 64 + wd] = word;
    }
    __syncthreads();

    {
        int w = tid >> 6, lane = tid & 63;
        float wa1_0 = Wa[lane], wa1_1 = Wa[lane + 64];
        float wa2_0 = Wa[FF + lane], wa2_1 = Wa[FF + lane + 64];
        for (int rr = 0; rr < 4; ++rr) {
            int rloc = w * 4 + rr;
            int row = r0 + rloc;
            float x0 = hs[rloc * FF + lane], x1 = hs[rloc * FF + lane + 64];
            float s1 = x0 * wa1_0 + x1 * wa1_1;
            float s2 = x0 * wa2_0 + x1 * wa2_1;
#pragma unroll
            for (int m = 32; m >= 1; m >>= 1) {
                s1 += __shfl_xor(s1, m, 64);
                s2 += __shfl_xor(s2, m, 64);
            }
            if (lane == 0) {
                f1[row] = s1;
                f2s[row] = s2 - SHIFT_C;
                f2a[row] = ALPHA * s2 - SHIFT_C;
            }
        }
    }

    int f4 = (tid & 31) * 4;
    int rg = tid >> 5;  // 0..7
    float acc[2][4];
#pragma unroll
    for (int rr = 0; rr < 2; ++rr)
#pragma unroll
        for (int cc = 0; cc < 4; ++cc) acc[rr][cc] = 0.f;

    for (int k0 = 0; k0 < FF; k0 += 4) {
        float4 wv[4];
#pragma unroll
        for (int kk = 0; kk < 4; ++kk)
            wv[kk] = *(const float4*)(W + (size_t)(k0 + kk) * FF + f4);
        float4 hv[2];
#pragma unroll
        for (int rr = 0; rr < 2; ++rr)
            hv[rr] = *(const float4*)(hs + (rg * 2 + rr) * FF + k0);
#pragma unroll
        for (int rr = 0; rr < 2; ++rr) {
            float hk[4] = {hv[rr].x, hv[rr].y, hv[rr].z, hv[rr].w};
#pragma unroll
            for (int kk = 0; kk < 4; ++kk) {
                acc[rr][0] += hk[kk] * wv[kk].x;
                acc[rr][1] += hk[kk] * wv[kk].y;
                acc[rr][2] += hk[kk] * wv[kk].z;
                acc[rr][3] += hk[kk] * wv[kk].w;
            }
        }
    }

    // LDS transpose + coalesced 16B stores
    __syncthreads();
    {
#pragma unroll
        for (int rr = 0; rr < 2; ++rr)
            *(float4*)(hs + (rg * 2 + rr) * 132 + f4) =
                make_float4(acc[rr][0], acc[rr][1], acc[rr][2], acc[rr][3]);
    }
    __syncthreads();
    {
        int fo = tid >> 1, jh = tid & 1;
        bf16x8 hv_, lv_;
#pragma unroll
        for (int jj = 0; jj < 8; ++jj) {
            float v = hs[(jh * 8 + jj) * 132 + fo];
            short hh = f2bf(v);
            hv_[jj] = hh;
            lv_[jj] = f2bf(v - bf2f(hh));
        }
        int b = r0 >> 11;
        int j0 = (r0 & (NN - 1)) + jh * 8;
        size_t off = (size_t)(b * FF + fo) * NP + j0;
        *(bf16x8*)(WhHiT + off) = hv_;
        *(bf16x8*)(WhLoT + off) = lv_;
    }
}

// ---------------------------------------------------------------------------
// k_attn v19 "cheap-EV on v15": v15's structural optimum (64 rows x 32 fo,
// EV-x4, 512 blocks, best measured 124.3) with the VALU itself cheapened:
// (1) EV = exp(max(f1+f2s, af1+f2a)) * mask -- constants folded in k_wh /
//     prologue, drops mul+sub (10.5 -> 7 ops/elem, -33% EV VALU);
// (2) row sums via one extra MFMA per A-fragment against all-ones B
//     (D[i][j] = rowsum(i) in every column; lane reg q = rowsum(kg*4+q),
//     layout-proof) -- removes the serial sp+= dependency chain and 16
//     adds/step for +4 MFMA/step (~0.8us). Denominator becomes sum of
//     bf16(p), CONSISTENT with the numerator's bf16(p).
// Interleaved one-A-live ordering (v17/v18-proven); live ~108 < 128, same
// reg class as v15 (4 waves/SIMD), no spill expected.
// ---------------------------------------------------------------------------
#define EV2(fs, fa, f1v, af1v, wv, bi) ({ \
    float _x = fmaxf((f1v) + (fs), (af1v) + (fa)); \
    __expf(_x) * (float)(((wv) >> (bi)) & 1u); })

#define BUILD_A2(Adst, F1V, AF1V, WV) { \
    float pa, pb; \
    pa = EV2(q0s.x, q0a.x, F1V, AF1V, WV, bb + 0); pb = EV2(q0s.y, q0a.y, F1V, AF1V, WV, bb + 1); \
    asm("v_cvt_pk_bf16_f32 %0, %1, %2" : "=v"(Adst.u[0]) : "v"(pa), "v"(pb)); \
    pa = EV2(q0s.z, q0a.z, F1V, AF1V, WV, bb + 2); pb = EV2(q0s.w, q0a.w, F1V, AF1V, WV, bb + 3); \
    asm("v_cvt_pk_bf16_f32 %0, %1, %2" : "=v"(Adst.u[1]) : "v"(pa), "v"(pb)); \
    pa = EV2(q1s.x, q1a.x, F1V, AF1V, WV, bb + 4); pb = EV2(q1s.y, q1a.y, F1V, AF1V, WV, bb + 5); \
    asm("v_cvt_pk_bf16_f32 %0, %1, %2" : "=v"(Adst.u[2]) : "v"(pa), "v"(pb)); \
    pa = EV2(q1s.z, q1a.z, F1V, AF1V, WV, bb + 6); pb = EV2(q1s.w, q1a.w, F1V, AF1V, WV, bb + 7); \
    asm("v_cvt_pk_bf16_f32 %0, %1, %2" : "=v"(Adst.u[3]) : "v"(pa), "v"(pb)); }

__global__ __launch_bounds__(512, 4) void k_attn(const short* __restrict__ WhHiT,
                                                 const short* __restrict__ WhLoT,
                                                 const u32* __restrict__ adjp,
                                                 const float* __restrict__ f1,
                                                 const float* __restrict__ f2s,
                                                 const float* __restrict__ f2a,
                                                 float* __restrict__ out) {
    __shared__ __align__(16) char lds[67840];  // 8 x 8KB images + row_ps[8][64] + row_inv[64]
    float* row_ps = (float*)(lds + 65536);     // [8][64]
    float* row_inv = (float*)(lds + 67584);    // [64]

    int tid = threadIdx.x;
    int w = tid >> 6, lane = tid & 63;
    int blk = blockIdx.x;                      // 512 = 4 b x 32 tile(64 rows) x 4 qt
    int b = blk >> 7;
    int tile = (blk >> 2) & 31;
    int qt = blk & 3;
    int i0 = tile * 64;

    int r_c = lane & 15, kg = lane >> 4;

    const float* f2sb = f2s + b * NN;
    const float* f2ab = f2a + b * NN;
    float f10 = f1[b * NN + i0 + r_c];
    float f11 = f1[b * NN + i0 + 16 + r_c];
    float f12 = f1[b * NN + i0 + 32 + r_c];
    float f13 = f1[b * NN + i0 + 48 + r_c];
    float af10 = ALPHA * f10, af11 = ALPHA * f11, af12 = ALPHA * f12, af13 = ALPHA * f13;
    const u32* ap0 = adjp + (size_t)(i0 + r_c) * 64;  // mi offset = mi*1024

    // B-fragment row pointers (hi); lo at constant element delta
    const ptrdiff_t dLo = (ptrdiff_t)BB * FF * NP;
    int s0 = w * 8;  // this wave's 8 contiguous j-steps
    const short* pB0 = WhHiT + (size_t)(b * FF + qt * 32 + 0 * 16 + r_c) * NP + s0 * 32 + kg * 8;
    const short* pB1 = WhHiT + (size_t)(b * FF + qt * 32 + 1 * 16 + r_c) * NP + s0 * 32 + kg * 8;

    union { u32 u[4]; bf16x8 v; } ones;
    ones.u[0] = ones.u[1] = ones.u[2] = ones.u[3] = 0x3F803F80u;  // bf16 1.0 x8

    f32x4 acc0_0 = {0,0,0,0}, acc0_1 = {0,0,0,0}, acc0_2 = {0,0,0,0}, acc0_3 = {0,0,0,0};
    f32x4 acc1_0 = {0,0,0,0}, acc1_1 = {0,0,0,0}, acc1_2 = {0,0,0,0}, acc1_3 = {0,0,0,0};
    f32x4 accs0 = {0,0,0,0}, accs1 = {0,0,0,0}, accs2 = {0,0,0,0}, accs3 = {0,0,0,0};

#pragma unroll
    for (int s8 = 0; s8 < 8; ++s8) {
        int s = s0 + s8;
        // scalars for this step (folded f2 arrays)
        float4 q0s = *(const float4*)(f2sb + s * 32 + kg * 8);
        float4 q1s = *(const float4*)(f2sb + s * 32 + kg * 8 + 4);
        float4 q0a = *(const float4*)(f2ab + s * 32 + kg * 8);
        float4 q1a = *(const float4*)(f2ab + s * 32 + kg * 8 + 4);
        u32 w0 = ap0[s], w1 = ap0[1024 + s], w2 = ap0[2048 + s], w3 = ap0[3072 + s];
        // B loads (4 x 16B pairs)
        bf16x8 bh0 = *(const bf16x8*)(pB0); bf16x8 bl0 = *(const bf16x8*)(pB0 + dLo);
        bf16x8 bh1 = *(const bf16x8*)(pB1); bf16x8 bl1 = *(const bf16x8*)(pB1 + dLo);

        int bb = kg * 8;
        // interleaved: one A-frag live at a time; ones-MFMA accumulates row sums
        {
            union { u32 u[4]; bf16x8 v; } A;
            BUILD_A2(A, f10, af10, w0)
            accs0  = __builtin_amdgcn_mfma_f32_16x16x32_bf16(A.v, ones.v, accs0, 0, 0, 0);
            acc0_0 = __builtin_amdgcn_mfma_f32_16x16x32_bf16(A.v, bh0, acc0_0, 0, 0, 0);
            acc0_0 = __builtin_amdgcn_mfma_f32_16x16x32_bf16(A.v, bl0, acc0_0, 0, 0, 0);
            acc1_0 = __builtin_amdgcn_mfma_f32_16x16x32_bf16(A.v, bh1, acc1_0, 0, 0, 0);
            acc1_0 = __builtin_amdgcn_mfma_f32_16x16x32_bf16(A.v, bl1, acc1_0, 0, 0, 0);
        }
        {
            union { u32 u[4]; bf16x8 v; } A;
            BUILD_A2(A, f11, af11, w1)
            accs1  = __builtin_amdgcn_mfma_f32_16x16x32_bf16(A.v, ones.v, accs1, 0, 0, 0);
            acc0_1 = __builtin_amdgcn_mfma_f32_16x16x32_bf16(A.v, bh0, acc0_1, 0, 0, 0);
            acc0_1 = __builtin_amdgcn_mfma_f32_16x16x32_bf16(A.v, bl0, acc0_1, 0, 0, 0);
            acc1_1 = __builtin_amdgcn_mfma_f32_16x16x32_bf16(A.v, bh1, acc1_1, 0, 0, 0);
            acc1_1 = __builtin_amdgcn_mfma_f32_16x16x32_bf16(A.v, bl1, acc1_1, 0, 0, 0);
        }
        {
            union { u32 u[4]; bf16x8 v; } A;
            BUILD_A2(A, f12, af12, w2)
            accs2  = __builtin_amdgcn_mfma_f32_16x16x32_bf16(A.v, ones.v, accs2, 0, 0, 0);
            acc0_2 = __builtin_amdgcn_mfma_f32_16x16x32_bf16(A.v, bh0, acc0_2, 0, 0, 0);
            acc0_2 = __builtin_amdgcn_mfma_f32_16x16x32_bf16(A.v, bl0, acc0_2, 0, 0, 0);
            acc1_2 = __builtin_amdgcn_mfma_f32_16x16x32_bf16(A.v, bh1, acc1_2, 0, 0, 0);
            acc1_2 = __builtin_amdgcn_mfma_f32_16x16x32_bf16(A.v, bl1, acc1_2, 0, 0, 0);
        }
        {
            union { u32 u[4]; bf16x8 v; } A;
            BUILD_A2(A, f13, af13, w3)
            accs3  = __builtin_amdgcn_mfma_f32_16x16x32_bf16(A.v, ones.v, accs3, 0, 0, 0);
            acc0_3 = __builtin_amdgcn_mfma_f32_16x16x32_bf16(A.v, bh0, acc0_3, 0, 0, 0);
            acc0_3 = __builtin_amdgcn_mfma_f32_16x16x32_bf16(A.v, bl0, acc0_3, 0, 0, 0);
            acc1_3 = __builtin_amdgcn_mfma_f32_16x16x32_bf16(A.v, bh1, acc1_3, 0, 0, 0);
            acc1_3 = __builtin_amdgcn_mfma_f32_16x16x32_bf16(A.v, bl1, acc1_3, 0, 0, 0);
        }

        pB0 += 32; pB1 += 32;
    }

    // ---- epilogue ----
    // row sums from the ones-MFMA: every column identical -> lane reg q holds
    // rowsum(mi*16 + kg*4 + q); lanes with r_c==0 (4 lanes, kg 0..3) write.
    if (r_c == 0) {
#pragma unroll
        for (int q = 0; q < 4; ++q) {
            row_ps[w * 64 +      kg * 4 + q] = accs0[q];
            row_ps[w * 64 + 16 + kg * 4 + q] = accs1[q];
            row_ps[w * 64 + 32 + kg * 4 + q] = accs2[q];
            row_ps[w * 64 + 48 + kg * 4 + q] = accs3[q];
        }
    }
    // write this wave's partial image: [32 cols][16 row-quads] f32x4, XOR-swizzled
    {
        char* img = lds + w * 8192;
#define STACC(NI, MI, A) { int ch = (((NI)*16 + r_c) * 16 + (MI)*4 + kg) ^ (r_c & 7); \
                           *(f32x4*)(img + ch * 16) = (A); }
        STACC(0, 0, acc0_0) STACC(0, 1, acc0_1) STACC(0, 2, acc0_2) STACC(0, 3, acc0_3)
        STACC(1, 0, acc1_0) STACC(1, 1, acc1_1) STACC(1, 2, acc1_2) STACC(1, 3, acc1_3)
#undef STACC
    }
    __syncthreads();
    if (tid < 64) {
        float t = 0.f;
#pragma unroll
        for (int ww = 0; ww < 8; ++ww) t += row_ps[ww * 64 + tid];
        row_inv[tid] = 1.0f / t;
    }
    __syncthreads();

    // merge 8 images + normalize + store.
    // wave w: cols w*4 + (lane>>4) (0..31 within quarter), row-quads rq = lane&15
    {
        int colg = w * 4 + (lane >> 4);
        int rq = lane & 15;
        int ch = (colg * 16 + rq) ^ (colg & 7);
        f32x4 v = {0, 0, 0, 0};
#pragma unroll
        for (int im = 0; im < 8; ++im)
            v += *(const f32x4*)(lds + im * 8192 + ch * 16);
        f32x4 rinv = *(const f32x4*)((char*)row_inv + rq * 16);
        float* ob = out + ((size_t)b * NN + i0 + rq * 4) * FF + qt * 32 + colg;
#pragma unroll
        for (int q = 0; q < 4; ++q)
            ob[(size_t)q * FF] = v[q] * rinv[q];
    }
}

// ---------------------------------------------------------------------------
extern "C" void kernel_launch(void* const* d_in, const int* in_sizes, int n_in,
                              void* d_out, int out_size, void* d_ws, size_t ws_size,
                              hipStream_t stream) {
    const float* h   = (const float*)d_in[0];
    const int*   adj = (const int*)d_in[1];
    const float* W   = (const float*)d_in[2];
    const float* a   = (const float*)d_in[3];
    float* out = (float*)d_out;

    short* WhHiT = (short*)d_ws;                          // 2.13 MB
    short* WhLoT = WhHiT + (size_t)BB * FF * NP;          // 2.13 MB
    float* f1  = (float*)(WhLoT + (size_t)BB * FF * NP);  // 32 KB
    float* f2s = f1 + (size_t)BB * NN;                    // 32 KB (f2 - 16)
    float* f2a = f2s + (size_t)BB * NN;                   // 32 KB (a*f2 - 16)
    u32* adjp = (u32*)(f2a + (size_t)BB * NN);            // 512 KB (total ~4.86 MB)

    k_wh<<<(BB * NN) / 16, 256, 0, stream>>>(h, W, a, adj, WhHiT, WhLoT, f1, f2s, f2a, adjp);
    k_attn<<<512, 512, 0, stream>>>(WhHiT, WhLoT, adjp, f1, f2s, f2a, out);
}

// Round 18
// 124.435 us; speedup vs baseline: 1.2936x; 1.2936x over previous
//
#include <hip/hip_runtime.h>

#define BB 4
#define NN 2048
#define FF 128
#define NP 2176  // padded WhT row stride (shorts)
#define ALPHA 0.2f
#define SHIFT_C 16.0f  // exp(x-16): x=LR(f1+f2) bounded ~|10|; masked -> p=0 via bit-multiply

typedef short bf16x8 __attribute__((ext_vector_type(8)));
typedef float f32x4 __attribute__((ext_vector_type(4)));
typedef unsigned u32;

__device__ inline short f2bf(float f) {  // RNE float -> bf16 bits
    union { float f; unsigned u; } v; v.f = f;
    unsigned r = (v.u + 0x7FFFu + ((v.u >> 16) & 1u)) >> 16;
    return (short)r;
}
__device__ inline float bf2f(short s) {
    union { float f; unsigned u; } v;
    v.u = ((unsigned)(unsigned short)s) << 16;
    return v.f;
}

// ---------------------------------------------------------------------------
// k_wh v2 (passed R11/R12/R14-R16).
// ---------------------------------------------------------------------------
__global__ __launch_bounds__(256) void k_wh(const float* __restrict__ h,
                                            const float* __restrict__ W,
                                            const float* __restrict__ a,
                                            const int* __restrict__ adj,
                                            short* __restrict__ WhHiT,
                                            short* __restrict__ WhLoT,
                                            float* __restrict__ f1,
                                            float* __restrict__ f2,
                                            u32* __restrict__ adjp) {
    __shared__ float Wa[2 * FF];
    __shared__ float hs[16 * 132];  // 8.25 KB
    int tid = threadIdx.x;
    int r0 = blockIdx.x * 16;

    {
        int fin = tid & 127;
        const float* av = (tid < 128) ? a : (a + FF);
        const float* wr = W + (size_t)fin * FF;
        float s = 0.f;
        for (int o = 0; o < FF; o += 4) {
            float4 wv = *(const float4*)(wr + o);
            float4 avv = *(const float4*)(av + o);
            s += wv.x * avv.x + wv.y * avv.y + wv.z * avv.z + wv.w * avv.w;
        }
        Wa[(tid < 128 ? 0 : FF) + fin] = s;
    }
    {
        const float4* src = (const float4*)(h + (size_t)r0 * FF);
        float4* dst = (float4*)hs;
        dst[tid] = src[tid];
        dst[256 + tid] = src[256 + tid];
    }
    {
        int g = blockIdx.x * 256 + tid;
        int row = g >> 6, wd = g & 63;
        const int4* ar = (const int4*)(adj + (size_t)row * NN + wd * 32);
        u32 word = 0;
#pragma unroll
        for (int q = 0; q < 8; ++q) {
            int4 v = ar[q];
            word |= (u32)(v.x > 0) << (q * 4);
            word |= (u32)(v.y > 0) << (q * 4 + 1);
            word |= (u32)(v.z > 0) << (q * 4 + 2);
            word |= (u32)(v.w > 0) << (q * 4 + 3);
        }
        adjp[row * 64 + wd] = word;
    }
    __syncthreads();

    {
        int w = tid >> 6, lane = tid & 63;
        float wa1_0 = Wa[lane], wa1_1 = Wa[lane + 64];
        float wa2_0 = Wa[FF + lane], wa2_1 = Wa[FF + lane + 64];
        for (int rr = 0; rr < 4; ++rr) {
            int rloc = w * 4 + rr;
            int row = r0 + rloc;
            float x0 = hs[rloc * FF + lane], x1 = hs[rloc * FF + lane + 64];
            float s1 = x0 * wa1_0 + x1 * wa1_1;
            float s2 = x0 * wa2_0 + x1 * wa2_1;
#pragma unroll
            for (int m = 32; m >= 1; m >>= 1) {
                s1 += __shfl_xor(s1, m, 64);
                s2 += __shfl_xor(s2, m, 64);
            }
            if (lane == 0) { f1[row] = s1; f2[row] = s2; }
        }
    }

    int f4 = (tid & 31) * 4;
    int rg = tid >> 5;  // 0..7
    float acc[2][4];
#pragma unroll
    for (int rr = 0; rr < 2; ++rr)
#pragma unroll
        for (int cc = 0; cc < 4; ++cc) acc[rr][cc] = 0.f;

    for (int k0 = 0; k0 < FF; k0 += 4) {
        float4 wv[4];
#pragma unroll
        for (int kk = 0; kk < 4; ++kk)
            wv[kk] = *(const float4*)(W + (size_t)(k0 + kk) * FF + f4);
        float4 hv[2];
#pragma unroll
        for (int rr = 0; rr < 2; ++rr)
            hv[rr] = *(const float4*)(hs + (rg * 2 + rr) * FF + k0);
#pragma unroll
        for (int rr = 0; rr < 2; ++rr) {
            float hk[4] = {hv[rr].x, hv[rr].y, hv[rr].z, hv[rr].w};
#pragma unroll
            for (int kk = 0; kk < 4; ++kk) {
                acc[rr][0] += hk[kk] * wv[kk].x;
                acc[rr][1] += hk[kk] * wv[kk].y;
                acc[rr][2] += hk[kk] * wv[kk].z;
                acc[rr][3] += hk[kk] * wv[kk].w;
            }
        }
    }

    // LDS transpose + coalesced 16B stores
    __syncthreads();
    {
#pragma unroll
        for (int rr = 0; rr < 2; ++rr)
            *(float4*)(hs + (rg * 2 + rr) * 132 + f4) =
                make_float4(acc[rr][0], acc[rr][1], acc[rr][2], acc[rr][3]);
    }
    __syncthreads();
    {
        int fo = tid >> 1, jh = tid & 1;
        bf16x8 hv_, lv_;
#pragma unroll
        for (int jj = 0; jj < 8; ++jj) {
            float v = hs[(jh * 8 + jj) * 132 + fo];
            short hh = f2bf(v);
            hv_[jj] = hh;
            lv_[jj] = f2bf(v - bf2f(hh));
        }
        int b = r0 >> 11;
        int j0 = (r0 & (NN - 1)) + jh * 8;
        size_t off = (size_t)(b * FF + fo) * NP + j0;
        *(bf16x8*)(WhHiT + off) = hv_;
        *(bf16x8*)(WhLoT + off) = lv_;
    }
}

// ---------------------------------------------------------------------------
// k_attn v15 (REVERT to R12 exactly -- session best, dur 124.3us, passed).
// 64-row x 32-fo re-tile of v8's wave-autonomous full-unroll structure.
// Block = 64 rows x 32 fo (512 blocks = 4b x 32 tiles x 4 fo-quarters;
// 2 blocks/CU). Per wave per step: 4 B-loads + 32 EV + 16 MFMA.
// Measured session matrix: fo=64 latency-bound (42us k_attn), fo=32 BEST
// (37us), fo=16 VALU-bound (57us); occupancy path closed by the 64-VGPR
// allocator attractor (spills at 65+ demand under any 8-waves/EU request:
// v9/v11/v12/v16/v19); EV cheapening spills (v19). v15 is the measured
// floor of this family: ~88us harness fills + ~6us k_wh + ~37us k_attn.
// ---------------------------------------------------------------------------
#define EV(f2v, f1v, wv, bi) ({ float _t = (f1v) + (f2v); float _x = fmaxf(_t, ALPHA * _t); \
    __expf(_x - SHIFT_C) * (float)(((wv) >> (bi)) & 1u); })

// one A-fragment build: 8 EV -> 4 cvt_pk words, accumulating into SP
#define BUILD_A(Adst, F1V, WV, SP) { \
    float pa, pb; \
    pa = EV(q0.x, F1V, WV, bb + 0); pb = EV(q0.y, F1V, WV, bb + 1); \
    SP += pa + pb; \
    asm("v_cvt_pk_bf16_f32 %0, %1, %2" : "=v"(Adst.u[0]) : "v"(pa), "v"(pb)); \
    pa = EV(q0.z, F1V, WV, bb + 2); pb = EV(q0.w, F1V, WV, bb + 3); \
    SP += pa + pb; \
    asm("v_cvt_pk_bf16_f32 %0, %1, %2" : "=v"(Adst.u[1]) : "v"(pa), "v"(pb)); \
    pa = EV(q1.x, F1V, WV, bb + 4); pb = EV(q1.y, F1V, WV, bb + 5); \
    SP += pa + pb; \
    asm("v_cvt_pk_bf16_f32 %0, %1, %2" : "=v"(Adst.u[2]) : "v"(pa), "v"(pb)); \
    pa = EV(q1.z, F1V, WV, bb + 6); pb = EV(q1.w, F1V, WV, bb + 7); \
    SP += pa + pb; \
    asm("v_cvt_pk_bf16_f32 %0, %1, %2" : "=v"(Adst.u[3]) : "v"(pa), "v"(pb)); }

__global__ __launch_bounds__(512, 4) void k_attn(const short* __restrict__ WhHiT,
                                                 const short* __restrict__ WhLoT,
                                                 const u32* __restrict__ adjp,
                                                 const float* __restrict__ f1,
                                                 const float* __restrict__ f2,
                                                 float* __restrict__ out) {
    __shared__ __align__(16) char lds[67840];  // 8 x 8KB images + row_ps[8][64] + row_inv[64]
    float* row_ps = (float*)(lds + 65536);     // [8][64]
    float* row_inv = (float*)(lds + 67584);    // [64]

    int tid = threadIdx.x;
    int w = tid >> 6, lane = tid & 63;
    int blk = blockIdx.x;                      // 512 = 4 b x 32 tile(64 rows) x 4 qt
    int b = blk >> 7;
    int tile = (blk >> 2) & 31;
    int qt = blk & 3;
    int i0 = tile * 64;

    int r_c = lane & 15, kg = lane >> 4;

    const float* f2b = f2 + b * NN;
    float f10 = f1[b * NN + i0 + r_c];
    float f11 = f1[b * NN + i0 + 16 + r_c];
    float f12 = f1[b * NN + i0 + 32 + r_c];
    float f13 = f1[b * NN + i0 + 48 + r_c];
    const u32* ap0 = adjp + (size_t)(i0 + r_c) * 64;
    const u32* ap1 = adjp + (size_t)(i0 + 16 + r_c) * 64;
    const u32* ap2 = adjp + (size_t)(i0 + 32 + r_c) * 64;
    const u32* ap3 = adjp + (size_t)(i0 + 48 + r_c) * 64;

    // B-fragment row pointers (hi); lo at constant element delta
    const ptrdiff_t dLo = (ptrdiff_t)BB * FF * NP;
    int s0 = w * 8;  // this wave's 8 contiguous j-steps
    const short* pB0 = WhHiT + (size_t)(b * FF + qt * 32 + 0 * 16 + r_c) * NP + s0 * 32 + kg * 8;
    const short* pB1 = WhHiT + (size_t)(b * FF + qt * 32 + 1 * 16 + r_c) * NP + s0 * 32 + kg * 8;

    f32x4 acc0_0 = {0,0,0,0}, acc0_1 = {0,0,0,0}, acc0_2 = {0,0,0,0}, acc0_3 = {0,0,0,0};
    f32x4 acc1_0 = {0,0,0,0}, acc1_1 = {0,0,0,0}, acc1_2 = {0,0,0,0}, acc1_3 = {0,0,0,0};
    float sp0 = 0.f, sp1 = 0.f, sp2 = 0.f, sp3 = 0.f;

    // prologue: scalars for step s0
    float4 q0 = *(const float4*)(f2b + s0 * 32 + kg * 8);
    float4 q1 = *(const float4*)(f2b + s0 * 32 + kg * 8 + 4);
    u32 w0 = ap0[s0], w1 = ap1[s0], w2 = ap2[s0], w3 = ap3[s0];

#pragma unroll
    for (int s8 = 0; s8 < 8; ++s8) {
        // B loads for this step (4 x 16B; consumed after ~700cy of e-compute)
        bf16x8 bh0 = *(const bf16x8*)(pB0); bf16x8 bl0 = *(const bf16x8*)(pB0 + dLo);
        bf16x8 bh1 = *(const bf16x8*)(pB1); bf16x8 bl1 = *(const bf16x8*)(pB1 + dLo);
        // prefetch next step's scalars (wrap harmless)
        int sn = (s0 + s8 + 1) & 63;
        float4 nq0 = *(const float4*)(f2b + sn * 32 + kg * 8);
        float4 nq1 = *(const float4*)(f2b + sn * 32 + kg * 8 + 4);
        u32 nw0 = ap0[sn], nw1 = ap1[sn], nw2 = ap2[sn], nw3 = ap3[sn];

        // in-register A fragments: lane holds rows mi*16 + r_c, k = s*32 + kg*8 + e
        union { u32 u[4]; bf16x8 v; } A0, A1, A2, A3;
        int bb = kg * 8;
        BUILD_A(A0, f10, w0, sp0)
        BUILD_A(A1, f11, w1, sp1)
        BUILD_A(A2, f12, w2, sp2)
        BUILD_A(A3, f13, w3, sp3)

        // 16 MFMA: acc{ni}_{mi} += A{mi} x (Bhi+Blo){ni}
        acc0_0 = __builtin_amdgcn_mfma_f32_16x16x32_bf16(A0.v, bh0, acc0_0, 0, 0, 0);
        acc0_0 = __builtin_amdgcn_mfma_f32_16x16x32_bf16(A0.v, bl0, acc0_0, 0, 0, 0);
        acc0_1 = __builtin_amdgcn_mfma_f32_16x16x32_bf16(A1.v, bh0, acc0_1, 0, 0, 0);
        acc0_1 = __builtin_amdgcn_mfma_f32_16x16x32_bf16(A1.v, bl0, acc0_1, 0, 0, 0);
        acc0_2 = __builtin_amdgcn_mfma_f32_16x16x32_bf16(A2.v, bh0, acc0_2, 0, 0, 0);
        acc0_2 = __builtin_amdgcn_mfma_f32_16x16x32_bf16(A2.v, bl0, acc0_2, 0, 0, 0);
        acc0_3 = __builtin_amdgcn_mfma_f32_16x16x32_bf16(A3.v, bh0, acc0_3, 0, 0, 0);
        acc0_3 = __builtin_amdgcn_mfma_f32_16x16x32_bf16(A3.v, bl0, acc0_3, 0, 0, 0);
        acc1_0 = __builtin_amdgcn_mfma_f32_16x16x32_bf16(A0.v, bh1, acc1_0, 0, 0, 0);
        acc1_0 = __builtin_amdgcn_mfma_f32_16x16x32_bf16(A0.v, bl1, acc1_0, 0, 0, 0);
        acc1_1 = __builtin_amdgcn_mfma_f32_16x16x32_bf16(A1.v, bh1, acc1_1, 0, 0, 0);
        acc1_1 = __builtin_amdgcn_mfma_f32_16x16x32_bf16(A1.v, bl1, acc1_1, 0, 0, 0);
        acc1_2 = __builtin_amdgcn_mfma_f32_16x16x32_bf16(A2.v, bh1, acc1_2, 0, 0, 0);
        acc1_2 = __builtin_amdgcn_mfma_f32_16x16x32_bf16(A2.v, bl1, acc1_2, 0, 0, 0);
        acc1_3 = __builtin_amdgcn_mfma_f32_16x16x32_bf16(A3.v, bh1, acc1_3, 0, 0, 0);
        acc1_3 = __builtin_amdgcn_mfma_f32_16x16x32_bf16(A3.v, bl1, acc1_3, 0, 0, 0);

        // advance
        pB0 += 32; pB1 += 32;
        q0 = nq0; q1 = nq1; w0 = nw0; w1 = nw1; w2 = nw2; w3 = nw3;
    }

    // ---- epilogue ----
    // row sums: lanes {r_c, +16, +32, +48} hold k-slices of the same rows
    sp0 += __shfl_xor(sp0, 16, 64); sp0 += __shfl_xor(sp0, 32, 64);
    sp1 += __shfl_xor(sp1, 16, 64); sp1 += __shfl_xor(sp1, 32, 64);
    sp2 += __shfl_xor(sp2, 16, 64); sp2 += __shfl_xor(sp2, 32, 64);
    sp3 += __shfl_xor(sp3, 16, 64); sp3 += __shfl_xor(sp3, 32, 64);
    if (lane < 16) {
        row_ps[w * 64 + lane]      = sp0;
        row_ps[w * 64 + 16 + lane] = sp1;
        row_ps[w * 64 + 32 + lane] = sp2;
        row_ps[w * 64 + 48 + lane] = sp3;
    }
    // write this wave's partial image: [32 cols][16 row-quads] f32x4, XOR-swizzled
    {
        char* img = lds + w * 8192;
#define STACC(NI, MI, A) { int ch = (((NI)*16 + r_c) * 16 + (MI)*4 + kg) ^ (r_c & 7); \
                           *(f32x4*)(img + ch * 16) = (A); }
        STACC(0, 0, acc0_0) STACC(0, 1, acc0_1) STACC(0, 2, acc0_2) STACC(0, 3, acc0_3)
        STACC(1, 0, acc1_0) STACC(1, 1, acc1_1) STACC(1, 2, acc1_2) STACC(1, 3, acc1_3)
#undef STACC
    }
    __syncthreads();
    if (tid < 64) {
        float t = 0.f;
#pragma unroll
        for (int ww = 0; ww < 8; ++ww) t += row_ps[ww * 64 + tid];
        row_inv[tid] = 1.0f / t;
    }
    __syncthreads();

    // merge 8 images + normalize + store.
    // wave w: cols w*4 + (lane>>4) (0..31 within quarter), row-quads rq = lane&15
    {
        int colg = w * 4 + (lane >> 4);
        int rq = lane & 15;
        int ch = (colg * 16 + rq) ^ (colg & 7);
        f32x4 v = {0, 0, 0, 0};
#pragma unroll
        for (int im = 0; im < 8; ++im)
            v += *(const f32x4*)(lds + im * 8192 + ch * 16);
        f32x4 rinv = *(const f32x4*)((char*)row_inv + rq * 16);
        float* ob = out + ((size_t)b * NN + i0 + rq * 4) * FF + qt * 32 + colg;
#pragma unroll
        for (int q = 0; q < 4; ++q)
            ob[(size_t)q * FF] = v[q] * rinv[q];
    }
}

// ---------------------------------------------------------------------------
extern "C" void kernel_launch(void* const* d_in, const int* in_sizes, int n_in,
                              void* d_out, int out_size, void* d_ws, size_t ws_size,
                              hipStream_t stream) {
    const float* h   = (const float*)d_in[0];
    const int*   adj = (const int*)d_in[1];
    const float* W   = (const float*)d_in[2];
    const float* a   = (const float*)d_in[3];
    float* out = (float*)d_out;

    short* WhHiT = (short*)d_ws;                          // 2.13 MB
    short* WhLoT = WhHiT + (size_t)BB * FF * NP;          // 2.13 MB
    float* f1 = (float*)(WhLoT + (size_t)BB * FF * NP);   // 32 KB
    float* f2 = f1 + (size_t)BB * NN;                     // 32 KB
    u32* adjp = (u32*)(f2 + (size_t)BB * NN);             // 512 KB (total ~4.83 MB, proven)

    k_wh<<<(BB * NN) / 16, 256, 0, stream>>>(h, W, a, adj, WhHiT, WhLoT, f1, f2, adjp);
    k_attn<<<512, 512, 0, stream>>>(WhHiT, WhLoT, adjp, f1, f2, out);
}